// Round 1
// baseline (565.906 us; speedup 1.0000x reference)
//
#include <hip/hip_runtime.h>

#define NN 100000      // nodes
#define DIN 128
#define DH 64
#define DOUT 32

typedef __attribute__((ext_vector_type(4))) float f32x4;
typedef __attribute__((ext_vector_type(8))) __bf16 bf16x8;
typedef __attribute__((ext_vector_type(8))) unsigned short u16x8;
typedef __attribute__((ext_vector_type(4))) unsigned short u16x4;

__device__ __forceinline__ unsigned short f2bf(float f) {
  unsigned u = __builtin_bit_cast(unsigned, f);
  u = (u + 0x7FFFu + ((u >> 16) & 1u)) >> 16;   // RNE
  return (unsigned short)u;
}

// ---- dtype detection: int64 edge_index has zero high words ----
__global__ void k_flag(const unsigned* e, int* flag) {
  if (threadIdx.x == 0 && blockIdx.x == 0) {
    int i64 = 1;
    for (int i = 0; i < 8; ++i) if (e[2 * i + 1] != 0u) i64 = 0;
    flag[0] = i64;
  }
}

__device__ __forceinline__ int edge_at(const void* ei, int flag, size_t idx) {
  if (flag) return (int)((const long long*)ei)[idx];
  return ((const int*)ei)[idx];
}

// ---- weight prep: combine W_l|W_r row-blocks, cast to bf16 [c][k] ----
__global__ void k_prep(const float* W1l, const float* W1r, const float* W2l,
                       const float* W2r, unsigned short* Wc1, unsigned short* Wc2) {
  int i = blockIdx.x * 256 + threadIdx.x;
  if (i < 128 * 128) {
    int c = i >> 7, k = i & 127;
    float v = (c < 64) ? W1l[c * 128 + k] : W1r[(c - 64) * 128 + k];
    Wc1[i] = f2bf(v);
  }
  if (i < 64 * 64) {
    int c = i >> 6, k = i & 63;
    float v = (c < 32) ? W2l[c * 64 + k] : W2r[(c - 32) * 64 + k];
    Wc2[i] = f2bf(v);
  }
}

// ---- CSR build ----
__global__ void k_deg(const void* ei, const int* flag, int* deg, int ne) {
  int e = blockIdx.x * 256 + threadIdx.x;
  if (e >= ne) return;
  int f = flag[0];
  int d = edge_at(ei, f, (size_t)ne + e);
  atomicAdd(&deg[d], 1);
}

__global__ __launch_bounds__(1024) void k_scan1(const int* deg, int* pre, int* bsum, int n) {
  __shared__ int s[1024];
  int t = threadIdx.x;
  int i = blockIdx.x * 1024 + t;
  int v = (i < n) ? deg[i] : 0;
  s[t] = v;
  __syncthreads();
  for (int off = 1; off < 1024; off <<= 1) {
    int tmp = 0;
    if (t >= off) tmp = s[t - off];
    __syncthreads();
    if (t >= off) s[t] += tmp;
    __syncthreads();
  }
  if (i < n) pre[i] = s[t] - v;          // block-local exclusive
  if (t == 1023) bsum[blockIdx.x] = s[t]; // block total
}

__global__ void k_scan2(int* bsum, int nb) {  // 1 block, 128 threads
  __shared__ int s[128];
  int t = threadIdx.x;
  int v = (t < nb) ? bsum[t] : 0;
  s[t] = v;
  __syncthreads();
  for (int off = 1; off < 128; off <<= 1) {
    int tmp = 0;
    if (t >= off) tmp = s[t - off];
    __syncthreads();
    if (t >= off) s[t] += tmp;
    __syncthreads();
  }
  if (t < nb) bsum[t] = s[t] - v;        // exclusive block offsets
}

__global__ __launch_bounds__(1024) void k_scan3(int* rowptr, int* cursor, const int* bsum,
                                                int n, int ne) {
  int i = blockIdx.x * 1024 + threadIdx.x;
  if (i < n) {
    int v = rowptr[i] + bsum[blockIdx.x];
    rowptr[i] = v;
    cursor[i] = v;
  }
  if (i == 0) rowptr[n] = ne;
}

__global__ void k_scatter(const void* ei, const int* flag, int* cursor, int* eidx, int ne) {
  int e = blockIdx.x * 256 + threadIdx.x;
  if (e >= ne) return;
  int f = flag[0];
  int s = edge_at(ei, f, (size_t)e);
  int d = edge_at(ei, f, (size_t)ne + e);
  int pos = atomicAdd(&cursor[d], 1);
  eidx[pos] = s;
}

// ---- bf16 MFMA GEMM: Y[n][c] = sum_k X[n][k] * Wc[c][k]  (B^T-input pattern) ----
// block = 256 thr (4 waves), MB=128 nodes/block; wave handles 32 nodes x NC cols.
template <int K, int NC, bool INBF16>
__global__ __launch_bounds__(256) void k_gemm(const void* Xv, const unsigned short* Wc,
                                              float* Y, int nrows) {
  constexpr int MB = 128;
  constexpr int KP = K + 8;  // +16B pad: conflict-free b128 reads
  __shared__ unsigned short xs[MB * KP];
  __shared__ unsigned short wb[NC * KP];
  const int t = threadIdx.x;
  const int node0 = blockIdx.x * MB;

  // stage W (bf16 in global already)
  for (int i = t; i < NC * K / 8; i += 256) {
    int r = i / (K / 8), c8 = i % (K / 8);
    u16x8 v = *(const u16x8*)(Wc + r * K + c8 * 8);
    *(u16x8*)(&wb[r * KP + c8 * 8]) = v;
  }
  // stage X
  if constexpr (!INBF16) {
    const float* X = (const float*)Xv;
    for (int i = t; i < MB * K / 4; i += 256) {
      int r = i / (K / 4), c4 = i % (K / 4);
      int row = node0 + r;
      f32x4 v = {0.f, 0.f, 0.f, 0.f};
      if (row < nrows) v = *(const f32x4*)(X + (size_t)row * K + c4 * 4);
      u16x4 b;
      b.x = f2bf(v.x); b.y = f2bf(v.y); b.z = f2bf(v.z); b.w = f2bf(v.w);
      *(u16x4*)(&xs[r * KP + c4 * 4]) = b;
    }
  } else {
    const unsigned short* X = (const unsigned short*)Xv;
    for (int i = t; i < MB * K / 8; i += 256) {
      int r = i / (K / 8), c8 = i % (K / 8);
      int row = node0 + r;
      u16x8 v = {0, 0, 0, 0, 0, 0, 0, 0};
      if (row < nrows) v = *(const u16x8*)(X + (size_t)row * K + c8 * 8);
      *(u16x8*)(&xs[r * KP + c8 * 8]) = v;
    }
  }
  __syncthreads();

  const int w = t >> 6, lane = t & 63;
  const int ln = lane & 15, q = lane >> 4;

  f32x4 acc[2][NC / 16] = {};
#pragma unroll
  for (int kt = 0; kt < K / 32; ++kt) {
    bf16x8 a0 = *(const bf16x8*)(&xs[(w * 32 + ln) * KP + kt * 32 + q * 8]);
    bf16x8 a1 = *(const bf16x8*)(&xs[(w * 32 + 16 + ln) * KP + kt * 32 + q * 8]);
#pragma unroll
    for (int ct = 0; ct < NC / 16; ++ct) {
      bf16x8 b = *(const bf16x8*)(&wb[(ct * 16 + ln) * KP + kt * 32 + q * 8]);
      acc[0][ct] = __builtin_amdgcn_mfma_f32_16x16x32_bf16(a0, b, acc[0][ct], 0, 0, 0);
      acc[1][ct] = __builtin_amdgcn_mfma_f32_16x16x32_bf16(a1, b, acc[1][ct], 0, 0, 0);
    }
  }
  // epilogue: D layout col=lane&15, row=(lane>>4)*4+reg  [m89/m91 verified]
#pragma unroll
  for (int nt = 0; nt < 2; ++nt)
#pragma unroll
    for (int ct = 0; ct < NC / 16; ++ct) {
      int row0 = node0 + w * 32 + nt * 16 + q * 4;
      int col = ct * 16 + ln;
#pragma unroll
      for (int r = 0; r < 4; ++r) {
        int row = row0 + r;
        if (row < nrows) Y[(size_t)row * NC + col] = acc[nt][ct][r];
      }
    }
}

// ---- layer-1 aggregate + bias + r-term + relu -> h (bf16) ----
// wave per node, lane = dim (64)
__global__ __launch_bounds__(256) void k_agg1(const float* Y1, const int* rowptr,
                                              const int* eidx, const float* b1,
                                              unsigned short* h, int n) {
  int gid = blockIdx.x * 4 + (threadIdx.x >> 6);
  int lane = threadIdx.x & 63;
  if (gid >= n) return;
  int beg = rowptr[gid], end = rowptr[gid + 1];
  float acc = 0.f;
  for (int j = beg; j < end; ++j) {
    int s = eidx[j];
    acc += Y1[(size_t)s * 128 + lane];     // l-part cols 0..63
  }
  int deg = end - beg;
  float inv = deg > 0 ? 1.f / (float)deg : 0.f;
  float v = acc * inv + b1[lane] + Y1[(size_t)gid * 128 + 64 + lane];  // r-part
  v = v > 0.f ? v : 0.f;                   // relu
  h[(size_t)gid * 64 + lane] = f2bf(v);
}

// ---- layer-2 aggregate + bias + r-term + log_softmax -> out ----
// wave per node; halves split neighbor list, lane&31 = dim
__global__ __launch_bounds__(256) void k_agg2(const float* Y2, const int* rowptr,
                                              const int* eidx, const float* b2,
                                              float* out, int n) {
  int gid = blockIdx.x * 4 + (threadIdx.x >> 6);
  int lane = threadIdx.x & 63;
  if (gid >= n) return;
  int beg = rowptr[gid], end = rowptr[gid + 1];
  int half = lane >> 5, l5 = lane & 31;
  float acc = 0.f;
  for (int j = beg + half; j < end; j += 2)
    acc += Y2[(size_t)eidx[j] * 64 + l5];  // l-part cols 0..31
  acc += __shfl_xor(acc, 32);
  int deg = end - beg;
  float inv = deg > 0 ? 1.f / (float)deg : 0.f;
  float v = acc * inv + b2[l5] + Y2[(size_t)gid * 64 + 32 + l5];
  float m = v;
#pragma unroll
  for (int off = 16; off; off >>= 1) m = fmaxf(m, __shfl_xor(m, off));
  float e = __expf(v - m);
  float ssum = e;
#pragma unroll
  for (int off = 16; off; off >>= 1) ssum += __shfl_xor(ssum, off);
  float o = v - m - __logf(ssum);
  if (lane < 32) out[(size_t)gid * 32 + l5] = o;
}

extern "C" void kernel_launch(void* const* d_in, const int* in_sizes, int n_in,
                              void* d_out, int out_size, void* d_ws, size_t ws_size,
                              hipStream_t stream) {
  const float* x = (const float*)d_in[0];
  const void* ei = d_in[1];
  const float* W1l = (const float*)d_in[2];
  const float* b1 = (const float*)d_in[3];
  const float* W1r = (const float*)d_in[4];
  const float* W2l = (const float*)d_in[5];
  const float* b2 = (const float*)d_in[6];
  const float* W2r = (const float*)d_in[7];
  const int n = NN;
  const int ne = in_sizes[1] / 2;

  char* base = (char*)d_ws;
  size_t off = 0;
  auto alloc = [&](size_t bytes) -> void* {
    void* r = base + off;
    off = (off + bytes + 255) & ~(size_t)255;
    return r;
  };
  int* flag = (int*)alloc(4);
  int* deg = (int*)alloc((size_t)n * 4);
  int* rowptr = (int*)alloc((size_t)(n + 1) * 4);
  int* cursor = (int*)alloc((size_t)n * 4);
  int* bsum = (int*)alloc(512);
  int* eidx = (int*)alloc((size_t)ne * 4);
  unsigned short* Wc1 = (unsigned short*)alloc(128 * 128 * 2);
  unsigned short* Wc2 = (unsigned short*)alloc(64 * 64 * 2);
  float* Y1 = (float*)alloc((size_t)n * 128 * 4);
  unsigned short* h = (unsigned short*)alloc((size_t)n * 64 * 2);
  float* Y2 = Y1;  // Y1 dead after k_agg1; reuse (stream-ordered)
  if (off > ws_size) return;  // insufficient workspace: fail cleanly

  hipMemsetAsync(deg, 0, (size_t)n * 4, stream);
  k_flag<<<1, 64, 0, stream>>>((const unsigned*)ei, flag);
  k_prep<<<64, 256, 0, stream>>>(W1l, W1r, W2l, W2r, Wc1, Wc2);
  k_deg<<<(ne + 255) / 256, 256, 0, stream>>>(ei, flag, deg, ne);
  int nb = (n + 1023) / 1024;
  k_scan1<<<nb, 1024, 0, stream>>>(deg, rowptr, bsum, n);
  k_scan2<<<1, 128, 0, stream>>>(bsum, nb);
  k_scan3<<<nb, 1024, 0, stream>>>(rowptr, cursor, bsum, n, ne);
  k_scatter<<<(ne + 255) / 256, 256, 0, stream>>>(ei, flag, cursor, eidx, ne);
  k_gemm<128, 128, false><<<(n + 127) / 128, 256, 0, stream>>>(x, Wc1, Y1, n);
  k_agg1<<<(n + 3) / 4, 256, 0, stream>>>(Y1, rowptr, eidx, b1, h, n);
  k_gemm<64, 64, true><<<(n + 127) / 128, 256, 0, stream>>>(h, Wc2, Y2, n);
  k_agg2<<<(n + 3) / 4, 256, 0, stream>>>(Y2, rowptr, eidx, b2, (float*)d_out, n);
}

// Round 2
// 443.660 us; speedup vs baseline: 1.2755x; 1.2755x over previous
//
#include <hip/hip_runtime.h>

#define NN 100000      // nodes

typedef __attribute__((ext_vector_type(4))) float f32x4;
typedef __attribute__((ext_vector_type(2))) float f32x2;
typedef __attribute__((ext_vector_type(8))) __bf16 bf16x8;
typedef __attribute__((ext_vector_type(8))) unsigned short u16x8;
typedef __attribute__((ext_vector_type(4))) unsigned short u16x4;

__device__ __forceinline__ unsigned short f2bf(float f) {
  unsigned u = __builtin_bit_cast(unsigned, f);
  u = (u + 0x7FFFu + ((u >> 16) & 1u)) >> 16;   // RNE
  return (unsigned short)u;
}
__device__ __forceinline__ float bflo(unsigned v) {
  return __builtin_bit_cast(float, v << 16);
}
__device__ __forceinline__ float bfhi(unsigned v) {
  return __builtin_bit_cast(float, v & 0xFFFF0000u);
}

__device__ __forceinline__ int edge_at(const void* ei, int flag, size_t idx) {
  if (flag) return (int)((const long long*)ei)[idx];
  return ((const int*)ei)[idx];
}

// ---- prep: edge dtype flag + zero deg + weight combine/cast ----
__global__ void k_prep(const float* W1l, const float* W1r, const float* W2l,
                       const float* W2r, unsigned short* Wc1, unsigned short* Wc2,
                       const unsigned* e, int* flag, int* deg, int n) {
  int i = blockIdx.x * 256 + threadIdx.x;
  if (i == 0) {
    int i64 = 1;
    for (int k = 0; k < 8; ++k) if (e[2 * k + 1] != 0u) i64 = 0;
    flag[0] = i64;
  }
  for (int j = i; j < n; j += 64 * 256) deg[j] = 0;
  if (i < 128 * 128) {
    int c = i >> 7, k = i & 127;
    float v = (c < 64) ? W1l[c * 128 + k] : W1r[(c - 64) * 128 + k];
    Wc1[i] = f2bf(v);
  }
  if (i < 64 * 64) {
    int c = i >> 6, k = i & 63;
    float v = (c < 32) ? W2l[c * 64 + k] : W2r[(c - 32) * 64 + k];
    Wc2[i] = f2bf(v);
  }
}

// ---- CSR build ----
__global__ void k_deg(const void* ei, const int* flag, int* deg, int ne) {
  int e = blockIdx.x * 256 + threadIdx.x;
  if (e >= ne) return;
  int f = flag[0];
  int d = edge_at(ei, f, (size_t)ne + e);
  atomicAdd(&deg[d], 1);
}

__global__ __launch_bounds__(1024) void k_scan1(const int* deg, int* pre, int* bsum, int n) {
  __shared__ int s[1024];
  int t = threadIdx.x;
  int i = blockIdx.x * 1024 + t;
  int v = (i < n) ? deg[i] : 0;
  s[t] = v;
  __syncthreads();
  for (int off = 1; off < 1024; off <<= 1) {
    int tmp = 0;
    if (t >= off) tmp = s[t - off];
    __syncthreads();
    if (t >= off) s[t] += tmp;
    __syncthreads();
  }
  if (i < n) pre[i] = s[t] - v;
  if (t == 1023) bsum[blockIdx.x] = s[t];
}

__global__ void k_scan2(int* bsum, int nb) {  // 1 block, 128 threads
  __shared__ int s[128];
  int t = threadIdx.x;
  int v = (t < nb) ? bsum[t] : 0;
  s[t] = v;
  __syncthreads();
  for (int off = 1; off < 128; off <<= 1) {
    int tmp = 0;
    if (t >= off) tmp = s[t - off];
    __syncthreads();
    if (t >= off) s[t] += tmp;
    __syncthreads();
  }
  if (t < nb) bsum[t] = s[t] - v;
}

__global__ __launch_bounds__(1024) void k_scan3(int* rowptr, int* cursor, const int* bsum,
                                                int n, int ne) {
  int i = blockIdx.x * 1024 + threadIdx.x;
  if (i < n) {
    int v = rowptr[i] + bsum[blockIdx.x];
    rowptr[i] = v;
    cursor[i] = v;
  }
  if (i == 0) rowptr[n] = ne;
}

__global__ void k_scatter(const void* ei, const int* flag, int* cursor, int* eidx, int ne) {
  int e = blockIdx.x * 256 + threadIdx.x;
  if (e >= ne) return;
  int f = flag[0];
  int s = edge_at(ei, f, (size_t)e);
  int d = edge_at(ei, f, (size_t)ne + e);
  int pos = atomicAdd(&cursor[d], 1);
  eidx[pos] = s;
}

// ---- bf16 MFMA GEMM: Y[n][c] = sum_k X[n][k] * Wc[c][k] ----
// split output: cols [0, NC/2) -> Yl (bf16, for gather), cols [NC/2, NC) -> Yr (f32)
template <int K, int NC, bool INBF16>
__global__ __launch_bounds__(256) void k_gemm(const void* Xv, const unsigned short* Wc,
                                              unsigned short* Yl, float* Yr, int nrows) {
  constexpr int MB = 128;
  constexpr int KP = K + 8;  // +16B pad: conflict-free b128 reads
  constexpr int HC = NC / 2;
  __shared__ unsigned short xs[MB * KP];
  __shared__ unsigned short wb[NC * KP];
  const int t = threadIdx.x;
  const int node0 = blockIdx.x * MB;

  for (int i = t; i < NC * K / 8; i += 256) {
    int r = i / (K / 8), c8 = i % (K / 8);
    u16x8 v = *(const u16x8*)(Wc + r * K + c8 * 8);
    *(u16x8*)(&wb[r * KP + c8 * 8]) = v;
  }
  if constexpr (!INBF16) {
    const float* X = (const float*)Xv;
    for (int i = t; i < MB * K / 4; i += 256) {
      int r = i / (K / 4), c4 = i % (K / 4);
      int row = node0 + r;
      f32x4 v = {0.f, 0.f, 0.f, 0.f};
      if (row < nrows) v = *(const f32x4*)(X + (size_t)row * K + c4 * 4);
      u16x4 b;
      b.x = f2bf(v.x); b.y = f2bf(v.y); b.z = f2bf(v.z); b.w = f2bf(v.w);
      *(u16x4*)(&xs[r * KP + c4 * 4]) = b;
    }
  } else {
    const unsigned short* X = (const unsigned short*)Xv;
    for (int i = t; i < MB * K / 8; i += 256) {
      int r = i / (K / 8), c8 = i % (K / 8);
      int row = node0 + r;
      u16x8 v = {0, 0, 0, 0, 0, 0, 0, 0};
      if (row < nrows) v = *(const u16x8*)(X + (size_t)row * K + c8 * 8);
      *(u16x8*)(&xs[r * KP + c8 * 8]) = v;
    }
  }
  __syncthreads();

  const int w = t >> 6, lane = t & 63;
  const int ln = lane & 15, q = lane >> 4;

  f32x4 acc[2][NC / 16] = {};
#pragma unroll
  for (int kt = 0; kt < K / 32; ++kt) {
    bf16x8 a0 = *(const bf16x8*)(&xs[(w * 32 + ln) * KP + kt * 32 + q * 8]);
    bf16x8 a1 = *(const bf16x8*)(&xs[(w * 32 + 16 + ln) * KP + kt * 32 + q * 8]);
#pragma unroll
    for (int ct = 0; ct < NC / 16; ++ct) {
      bf16x8 b = *(const bf16x8*)(&wb[(ct * 16 + ln) * KP + kt * 32 + q * 8]);
      acc[0][ct] = __builtin_amdgcn_mfma_f32_16x16x32_bf16(a0, b, acc[0][ct], 0, 0, 0);
      acc[1][ct] = __builtin_amdgcn_mfma_f32_16x16x32_bf16(a1, b, acc[1][ct], 0, 0, 0);
    }
  }
  // D layout: col=lane&15, row=(lane>>4)*4+reg  [m89/m91 verified]
#pragma unroll
  for (int nt = 0; nt < 2; ++nt)
#pragma unroll
    for (int ct = 0; ct < NC / 16; ++ct) {
      int row0 = node0 + w * 32 + nt * 16 + q * 4;
      int col = ct * 16 + ln;
#pragma unroll
      for (int r = 0; r < 4; ++r) {
        int row = row0 + r;
        if (row < nrows) {
          if (ct < NC / 32)
            Yl[(size_t)row * HC + col] = f2bf(acc[nt][ct][r]);
          else
            Yr[(size_t)row * HC + col - HC] = acc[nt][ct][r];
        }
      }
    }
}

// ---- layer-1: mean-gather(bf16 pairs) + bias + r-term + relu -> h (bf16) ----
// wave per node; half-wave per neighbor, lane&31 = dim-pair
__global__ __launch_bounds__(256) void k_agg1(const unsigned* Y1l, const float* Y1r,
                                              const int* rowptr, const int* eidx,
                                              const float* b1, unsigned* h, int n) {
  int gid = blockIdx.x * 4 + (threadIdx.x >> 6);
  int lane = threadIdx.x & 63;
  if (gid >= n) return;
  int beg = rowptr[gid], end = rowptr[gid + 1];
  int half = lane >> 5, l5 = lane & 31;
  float a0 = 0.f, a1 = 0.f;
  int j = beg + half;
  for (; j + 6 < end; j += 8) {   // 4 gathers in flight per half-wave
    int s0 = eidx[j], s1 = eidx[j + 2], s2 = eidx[j + 4], s3 = eidx[j + 6];
    unsigned v0 = Y1l[(size_t)s0 * 32 + l5];
    unsigned v1 = Y1l[(size_t)s1 * 32 + l5];
    unsigned v2 = Y1l[(size_t)s2 * 32 + l5];
    unsigned v3 = Y1l[(size_t)s3 * 32 + l5];
    a0 += (bflo(v0) + bflo(v1)) + (bflo(v2) + bflo(v3));
    a1 += (bfhi(v0) + bfhi(v1)) + (bfhi(v2) + bfhi(v3));
  }
  for (; j < end; j += 2) {
    unsigned v = Y1l[(size_t)eidx[j] * 32 + l5];
    a0 += bflo(v);
    a1 += bfhi(v);
  }
  a0 += __shfl_xor(a0, 32);
  a1 += __shfl_xor(a1, 32);
  if (lane < 32) {
    int deg = end - beg;
    float inv = deg > 0 ? 1.f / (float)deg : 0.f;
    f32x2 r = *(const f32x2*)(Y1r + (size_t)gid * 64 + 2 * l5);
    f32x2 bb = *(const f32x2*)(b1 + 2 * l5);
    float v0 = a0 * inv + bb.x + r.x;
    float v1 = a1 * inv + bb.y + r.y;
    v0 = v0 > 0.f ? v0 : 0.f;
    v1 = v1 > 0.f ? v1 : 0.f;
    h[(size_t)gid * 32 + l5] = (unsigned)f2bf(v0) | ((unsigned)f2bf(v1) << 16);
  }
}

// ---- layer-2: mean-gather + bias + r-term + log_softmax -> out ----
// wave per node; quarter-wave per neighbor, lane&15 = dim-pair
__global__ __launch_bounds__(256) void k_agg2(const unsigned* Y2l, const float* Y2r,
                                              const int* rowptr, const int* eidx,
                                              const float* b2, float* out, int n) {
  int gid = blockIdx.x * 4 + (threadIdx.x >> 6);
  int lane = threadIdx.x & 63;
  if (gid >= n) return;
  int beg = rowptr[gid], end = rowptr[gid + 1];
  int grp = lane >> 4, l4 = lane & 15;
  float a0 = 0.f, a1 = 0.f;
  int j = beg + grp;
  for (; j + 4 < end; j += 8) {   // 2 gathers in flight per quarter-wave (8/wave)
    int s0 = eidx[j], s1 = eidx[j + 4];
    unsigned v0 = Y2l[(size_t)s0 * 16 + l4];
    unsigned v1 = Y2l[(size_t)s1 * 16 + l4];
    a0 += bflo(v0) + bflo(v1);
    a1 += bfhi(v0) + bfhi(v1);
  }
  for (; j < end; j += 4) {
    unsigned v = Y2l[(size_t)eidx[j] * 16 + l4];
    a0 += bflo(v);
    a1 += bfhi(v);
  }
  a0 += __shfl_xor(a0, 32); a0 += __shfl_xor(a0, 16);
  a1 += __shfl_xor(a1, 32); a1 += __shfl_xor(a1, 16);
  int deg = end - beg;
  float inv = deg > 0 ? 1.f / (float)deg : 0.f;
  f32x2 r = *(const f32x2*)(Y2r + (size_t)gid * 32 + 2 * l4);
  f32x2 bb = *(const f32x2*)(b2 + 2 * l4);
  float v0 = a0 * inv + bb.x + r.x;
  float v1 = a1 * inv + bb.y + r.y;
  float m = fmaxf(v0, v1);
#pragma unroll
  for (int off = 8; off; off >>= 1) m = fmaxf(m, __shfl_xor(m, off));
  float e0 = __expf(v0 - m), e1 = __expf(v1 - m);
  float ss = e0 + e1;
#pragma unroll
  for (int off = 8; off; off >>= 1) ss += __shfl_xor(ss, off);
  float lg = __logf(ss);
  if (lane < 16) {
    f32x2 o = {v0 - m - lg, v1 - m - lg};
    *(f32x2*)(out + (size_t)gid * 32 + 2 * l4) = o;
  }
}

extern "C" void kernel_launch(void* const* d_in, const int* in_sizes, int n_in,
                              void* d_out, int out_size, void* d_ws, size_t ws_size,
                              hipStream_t stream) {
  const float* x = (const float*)d_in[0];
  const void* ei = d_in[1];
  const float* W1l = (const float*)d_in[2];
  const float* b1 = (const float*)d_in[3];
  const float* W1r = (const float*)d_in[4];
  const float* W2l = (const float*)d_in[5];
  const float* b2 = (const float*)d_in[6];
  const float* W2r = (const float*)d_in[7];
  const int n = NN;
  const int ne = in_sizes[1] / 2;

  char* base = (char*)d_ws;
  size_t off = 0;
  auto alloc = [&](size_t bytes) -> void* {
    void* r = base + off;
    off = (off + bytes + 255) & ~(size_t)255;
    return r;
  };
  int* flag = (int*)alloc(4);
  int* deg = (int*)alloc((size_t)n * 4);
  int* rowptr = (int*)alloc((size_t)(n + 1) * 4);
  int* cursor = (int*)alloc((size_t)n * 4);
  int* bsum = (int*)alloc(512);
  int* eidx = (int*)alloc((size_t)ne * 4);
  unsigned short* Wc1 = (unsigned short*)alloc(128 * 128 * 2);
  unsigned short* Wc2 = (unsigned short*)alloc(64 * 64 * 2);
  unsigned short* Y1l = (unsigned short*)alloc((size_t)n * 64 * 2);  // bf16 gather table
  float* Y1r = (float*)alloc((size_t)n * 64 * 4);
  unsigned* h = (unsigned*)alloc((size_t)n * 64 * 2);
  unsigned short* Y2l = (unsigned short*)alloc((size_t)n * 32 * 2);
  float* Y2r = (float*)alloc((size_t)n * 32 * 4);
  if (off > ws_size) return;

  k_prep<<<64, 256, 0, stream>>>(W1l, W1r, W2l, W2r, Wc1, Wc2,
                                 (const unsigned*)ei, flag, deg, n);
  k_deg<<<(ne + 255) / 256, 256, 0, stream>>>(ei, flag, deg, ne);
  int nb = (n + 1023) / 1024;
  k_scan1<<<nb, 1024, 0, stream>>>(deg, rowptr, bsum, n);
  k_scan2<<<1, 128, 0, stream>>>(bsum, nb);
  k_scan3<<<nb, 1024, 0, stream>>>(rowptr, cursor, bsum, n, ne);
  k_scatter<<<(ne + 255) / 256, 256, 0, stream>>>(ei, flag, cursor, eidx, ne);
  k_gemm<128, 128, false><<<(n + 127) / 128, 256, 0, stream>>>(x, Wc1, Y1l, Y1r, n);
  k_agg1<<<(n + 3) / 4, 256, 0, stream>>>((const unsigned*)Y1l, Y1r, rowptr, eidx, b1, h, n);
  k_gemm<64, 64, true><<<(n + 127) / 128, 256, 0, stream>>>(h, Wc2, Y2l, Y2r, n);
  k_agg2<<<(n + 3) / 4, 256, 0, stream>>>((const unsigned*)Y2l, Y2r, rowptr, eidx, b2,
                                          (float*)d_out, n);
}

// Round 3
// 305.631 us; speedup vs baseline: 1.8516x; 1.4516x over previous
//
#include <hip/hip_runtime.h>

#define NN 100000      // nodes (< 2^17 — required by the 4B packed bin record)
#define NBKT ((NN + 255) / 256)   // 391 dst-buckets of 256 nodes

typedef __attribute__((ext_vector_type(4))) float f32x4;
typedef __attribute__((ext_vector_type(2))) float f32x2;
typedef __attribute__((ext_vector_type(8))) __bf16 bf16x8;
typedef __attribute__((ext_vector_type(8))) unsigned short u16x8;
typedef __attribute__((ext_vector_type(4))) unsigned short u16x4;

__device__ __forceinline__ unsigned short f2bf(float f) {
  unsigned u = __builtin_bit_cast(unsigned, f);
  u = (u + 0x7FFFu + ((u >> 16) & 1u)) >> 16;   // RNE
  return (unsigned short)u;
}
__device__ __forceinline__ float bflo(unsigned v) {
  return __builtin_bit_cast(float, v << 16);
}
__device__ __forceinline__ float bfhi(unsigned v) {
  return __builtin_bit_cast(float, v & 0xFFFF0000u);
}

__device__ __forceinline__ int edge_at(const void* ei, int flag, size_t idx) {
  if (flag) return (int)((const long long*)ei)[idx];
  return ((const int*)ei)[idx];
}

// ---- prep: edge dtype flag + zero bucket counts + weight combine/cast ----
__global__ void k_prep(const float* W1l, const float* W1r, const float* W2l,
                       const float* W2r, unsigned short* Wc1, unsigned short* Wc2,
                       const unsigned* e, int* flag, int* bcnt) {
  int i = blockIdx.x * 256 + threadIdx.x;
  if (i == 0) {
    int i64 = 1;
    for (int k = 0; k < 8; ++k) if (e[2 * k + 1] != 0u) i64 = 0;
    flag[0] = i64;
  }
  if (i < 512) bcnt[i] = 0;
  if (i < 128 * 128) {
    int c = i >> 7, k = i & 127;
    float v = (c < 64) ? W1l[c * 128 + k] : W1r[(c - 64) * 128 + k];
    Wc1[i] = f2bf(v);
  }
  if (i < 64 * 64) {
    int c = i >> 6, k = i & 63;
    float v = (c < 32) ? W2l[c * 64 + k] : W2r[(c - 32) * 64 + k];
    Wc2[i] = f2bf(v);
  }
}

// ---- CSR build, phase 1: bucket histogram (LDS-staged) ----
__global__ __launch_bounds__(256) void k_bhist(const void* ei, const int* flag,
                                               int* bcnt, int ne, int nb) {
  __shared__ int h[512];
  int t = threadIdx.x;
  for (int i = t; i < nb; i += 256) h[i] = 0;
  __syncthreads();
  int f = flag[0];
  int stride = gridDim.x * 256;
  for (int e = blockIdx.x * 256 + t; e < ne; e += stride) {
    int d = edge_at(ei, f, (size_t)ne + e);
    atomicAdd(&h[d >> 8], 1);
  }
  __syncthreads();
  for (int i = t; i < nb; i += 256)
    if (h[i]) atomicAdd(&bcnt[i], h[i]);
}

// ---- phase 2: bucket exclusive scan -> bbase[nb+1], init gcur ----
__global__ __launch_bounds__(512) void k_bscan(const int* bcnt, int* bbase, int* gcur,
                                               int nb, int ne) {
  __shared__ int s[512];
  int t = threadIdx.x;
  int v = (t < nb) ? bcnt[t] : 0;
  s[t] = v;
  __syncthreads();
  for (int off = 1; off < 512; off <<= 1) {
    int tmp = (t >= off) ? s[t - off] : 0;
    __syncthreads();
    if (t >= off) s[t] += tmp;
    __syncthreads();
  }
  if (t < nb) {
    int excl = s[t] - v;
    bbase[t] = excl;
    gcur[t] = excl;
  }
  if (t == 0) bbase[nb] = ne;
}

// ---- phase 3: bin edges into bucket-contiguous 4B records ----
#define BIN_CHUNK 8192
__global__ __launch_bounds__(256) void k_bin(const void* ei, const int* flag, int* gcur,
                                             unsigned* binbuf, int ne, int nb) {
  __shared__ int hist[512];
  __shared__ int base[512];
  int t = threadIdx.x;
  int c0 = blockIdx.x * BIN_CHUNK;
  int cend = c0 + BIN_CHUNK < ne ? c0 + BIN_CHUNK : ne;
  int f = flag[0];
  for (int i = t; i < nb; i += 256) hist[i] = 0;
  __syncthreads();
  for (int e = c0 + t; e < cend; e += 256) {
    int d = edge_at(ei, f, (size_t)ne + e);
    atomicAdd(&hist[d >> 8], 1);
  }
  __syncthreads();
  for (int i = t; i < nb; i += 256) {
    int c = hist[i];
    base[i] = c ? atomicAdd(&gcur[i], c) : 0;
    hist[i] = 0;    // reuse as intra-block offset
  }
  __syncthreads();
  for (int e = c0 + t; e < cend; e += 256) {
    int d = edge_at(ei, f, (size_t)ne + e);
    int s = edge_at(ei, f, (size_t)e);
    int b = d >> 8;
    int off = atomicAdd(&hist[b], 1);
    binbuf[base[b] + off] = (unsigned)s | ((unsigned)(d & 255) << 17);
  }
}

// ---- phase 4: per-bucket block -> rowptr + eidx (all LDS cursors, L2-local writes) ----
__global__ __launch_bounds__(256) void k_build(const unsigned* binbuf, const int* bbase,
                                               int* rowptr, int* eidx, int n, int nb,
                                               int ne) {
  __shared__ int sdeg[256];
  __shared__ int soff[256];
  __shared__ int scur[256];
  int b = blockIdx.x;
  int t = threadIdx.x;
  int base = bbase[b];
  int cnt = bbase[b + 1] - base;
  sdeg[t] = 0;
  __syncthreads();
  for (int i = t; i < cnt; i += 256) {
    unsigned r = binbuf[base + i];
    atomicAdd(&sdeg[r >> 17], 1);
  }
  __syncthreads();
  int v = sdeg[t];
  soff[t] = v;
  __syncthreads();
  for (int off = 1; off < 256; off <<= 1) {
    int tmp = (t >= off) ? soff[t - off] : 0;
    __syncthreads();
    if (t >= off) soff[t] += tmp;
    __syncthreads();
  }
  int excl = soff[t] - v;    // exclusive local offset
  scur[t] = 0;
  int node = b * 256 + t;
  if (node < n) rowptr[node] = base + excl;
  if (b == nb - 1 && t == 0) rowptr[n] = ne;
  __syncthreads();
  soff[t] = excl;
  __syncthreads();
  for (int i = t; i < cnt; i += 256) {
    unsigned r = binbuf[base + i];
    int dl = r >> 17;
    eidx[base + soff[dl] + atomicAdd(&scur[dl], 1)] = (int)(r & 0x1FFFF);
  }
}

// ---- bf16 MFMA GEMM: Y[n][c] = sum_k X[n][k] * Wc[c][k] ----
// split output: cols [0, NC/2) -> Yl (bf16, for gather), cols [NC/2, NC) -> Yr (f32)
template <int K, int NC, bool INBF16>
__global__ __launch_bounds__(256) void k_gemm(const void* Xv, const unsigned short* Wc,
                                              unsigned short* Yl, float* Yr, int nrows) {
  constexpr int MB = 128;
  constexpr int KP = K + 8;  // +16B pad: conflict-free b128 reads
  constexpr int HC = NC / 2;
  __shared__ unsigned short xs[MB * KP];
  __shared__ unsigned short wb[NC * KP];
  const int t = threadIdx.x;
  const int node0 = blockIdx.x * MB;

  for (int i = t; i < NC * K / 8; i += 256) {
    int r = i / (K / 8), c8 = i % (K / 8);
    u16x8 v = *(const u16x8*)(Wc + r * K + c8 * 8);
    *(u16x8*)(&wb[r * KP + c8 * 8]) = v;
  }
  if constexpr (!INBF16) {
    const float* X = (const float*)Xv;
    for (int i = t; i < MB * K / 4; i += 256) {
      int r = i / (K / 4), c4 = i % (K / 4);
      int row = node0 + r;
      f32x4 v = {0.f, 0.f, 0.f, 0.f};
      if (row < nrows) v = *(const f32x4*)(X + (size_t)row * K + c4 * 4);
      u16x4 b;
      b.x = f2bf(v.x); b.y = f2bf(v.y); b.z = f2bf(v.z); b.w = f2bf(v.w);
      *(u16x4*)(&xs[r * KP + c4 * 4]) = b;
    }
  } else {
    const unsigned short* X = (const unsigned short*)Xv;
    for (int i = t; i < MB * K / 8; i += 256) {
      int r = i / (K / 8), c8 = i % (K / 8);
      int row = node0 + r;
      u16x8 v = {0, 0, 0, 0, 0, 0, 0, 0};
      if (row < nrows) v = *(const u16x8*)(X + (size_t)row * K + c8 * 8);
      *(u16x8*)(&xs[r * KP + c8 * 8]) = v;
    }
  }
  __syncthreads();

  const int w = t >> 6, lane = t & 63;
  const int ln = lane & 15, q = lane >> 4;

  f32x4 acc[2][NC / 16] = {};
#pragma unroll
  for (int kt = 0; kt < K / 32; ++kt) {
    bf16x8 a0 = *(const bf16x8*)(&xs[(w * 32 + ln) * KP + kt * 32 + q * 8]);
    bf16x8 a1 = *(const bf16x8*)(&xs[(w * 32 + 16 + ln) * KP + kt * 32 + q * 8]);
#pragma unroll
    for (int ct = 0; ct < NC / 16; ++ct) {
      bf16x8 b = *(const bf16x8*)(&wb[(ct * 16 + ln) * KP + kt * 32 + q * 8]);
      acc[0][ct] = __builtin_amdgcn_mfma_f32_16x16x32_bf16(a0, b, acc[0][ct], 0, 0, 0);
      acc[1][ct] = __builtin_amdgcn_mfma_f32_16x16x32_bf16(a1, b, acc[1][ct], 0, 0, 0);
    }
  }
  // D layout: col=lane&15, row=(lane>>4)*4+reg  [m89/m91 verified]
#pragma unroll
  for (int nt = 0; nt < 2; ++nt)
#pragma unroll
    for (int ct = 0; ct < NC / 16; ++ct) {
      int row0 = node0 + w * 32 + nt * 16 + q * 4;
      int col = ct * 16 + ln;
#pragma unroll
      for (int r = 0; r < 4; ++r) {
        int row = row0 + r;
        if (row < nrows) {
          if (ct < NC / 32)
            Yl[(size_t)row * HC + col] = f2bf(acc[nt][ct][r]);
          else
            Yr[(size_t)row * HC + col - HC] = acc[nt][ct][r];
        }
      }
    }
}

// ---- layer-1: mean-gather(bf16 pairs) + bias + r-term + relu -> h (bf16) ----
// wave per node; half-wave per neighbor, lane&31 = dim-pair
__global__ __launch_bounds__(256) void k_agg1(const unsigned* Y1l, const float* Y1r,
                                              const int* rowptr, const int* eidx,
                                              const float* b1, unsigned* h, int n) {
  int gid = blockIdx.x * 4 + (threadIdx.x >> 6);
  int lane = threadIdx.x & 63;
  if (gid >= n) return;
  int beg = rowptr[gid], end = rowptr[gid + 1];
  int half = lane >> 5, l5 = lane & 31;
  float a0 = 0.f, a1 = 0.f;
  int j = beg + half;
  for (; j + 6 < end; j += 8) {   // 4 gathers in flight per half-wave
    int s0 = eidx[j], s1 = eidx[j + 2], s2 = eidx[j + 4], s3 = eidx[j + 6];
    unsigned v0 = Y1l[(size_t)s0 * 32 + l5];
    unsigned v1 = Y1l[(size_t)s1 * 32 + l5];
    unsigned v2 = Y1l[(size_t)s2 * 32 + l5];
    unsigned v3 = Y1l[(size_t)s3 * 32 + l5];
    a0 += (bflo(v0) + bflo(v1)) + (bflo(v2) + bflo(v3));
    a1 += (bfhi(v0) + bfhi(v1)) + (bfhi(v2) + bfhi(v3));
  }
  for (; j < end; j += 2) {
    unsigned v = Y1l[(size_t)eidx[j] * 32 + l5];
    a0 += bflo(v);
    a1 += bfhi(v);
  }
  a0 += __shfl_xor(a0, 32);
  a1 += __shfl_xor(a1, 32);
  if (lane < 32) {
    int deg = end - beg;
    float inv = deg > 0 ? 1.f / (float)deg : 0.f;
    f32x2 r = *(const f32x2*)(Y1r + (size_t)gid * 64 + 2 * l5);
    f32x2 bb = *(const f32x2*)(b1 + 2 * l5);
    float v0 = a0 * inv + bb.x + r.x;
    float v1 = a1 * inv + bb.y + r.y;
    v0 = v0 > 0.f ? v0 : 0.f;
    v1 = v1 > 0.f ? v1 : 0.f;
    h[(size_t)gid * 32 + l5] = (unsigned)f2bf(v0) | ((unsigned)f2bf(v1) << 16);
  }
}

// ---- layer-2: mean-gather + bias + r-term + log_softmax -> out ----
// wave per node; quarter-wave per neighbor, lane&15 = dim-pair
__global__ __launch_bounds__(256) void k_agg2(const unsigned* Y2l, const float* Y2r,
                                              const int* rowptr, const int* eidx,
                                              const float* b2, float* out, int n) {
  int gid = blockIdx.x * 4 + (threadIdx.x >> 6);
  int lane = threadIdx.x & 63;
  if (gid >= n) return;
  int beg = rowptr[gid], end = rowptr[gid + 1];
  int grp = lane >> 4, l4 = lane & 15;
  float a0 = 0.f, a1 = 0.f;
  int j = beg + grp;
  for (; j + 4 < end; j += 8) {   // 2 gathers in flight per quarter-wave (8/wave)
    int s0 = eidx[j], s1 = eidx[j + 4];
    unsigned v0 = Y2l[(size_t)s0 * 16 + l4];
    unsigned v1 = Y2l[(size_t)s1 * 16 + l4];
    a0 += bflo(v0) + bflo(v1);
    a1 += bfhi(v0) + bfhi(v1);
  }
  for (; j < end; j += 4) {
    unsigned v = Y2l[(size_t)eidx[j] * 16 + l4];
    a0 += bflo(v);
    a1 += bfhi(v);
  }
  a0 += __shfl_xor(a0, 32); a0 += __shfl_xor(a0, 16);
  a1 += __shfl_xor(a1, 32); a1 += __shfl_xor(a1, 16);
  int deg = end - beg;
  float inv = deg > 0 ? 1.f / (float)deg : 0.f;
  f32x2 r = *(const f32x2*)(Y2r + (size_t)gid * 32 + 2 * l4);
  f32x2 bb = *(const f32x2*)(b2 + 2 * l4);
  float v0 = a0 * inv + bb.x + r.x;
  float v1 = a1 * inv + bb.y + r.y;
  float m = fmaxf(v0, v1);
#pragma unroll
  for (int off = 8; off; off >>= 1) m = fmaxf(m, __shfl_xor(m, off));
  float e0 = __expf(v0 - m), e1 = __expf(v1 - m);
  float ss = e0 + e1;
#pragma unroll
  for (int off = 8; off; off >>= 1) ss += __shfl_xor(ss, off);
  float lg = __logf(ss);
  if (lane < 16) {
    f32x2 o = {v0 - m - lg, v1 - m - lg};
    *(f32x2*)(out + (size_t)gid * 32 + 2 * l4) = o;
  }
}

extern "C" void kernel_launch(void* const* d_in, const int* in_sizes, int n_in,
                              void* d_out, int out_size, void* d_ws, size_t ws_size,
                              hipStream_t stream) {
  const float* x = (const float*)d_in[0];
  const void* ei = d_in[1];
  const float* W1l = (const float*)d_in[2];
  const float* b1 = (const float*)d_in[3];
  const float* W1r = (const float*)d_in[4];
  const float* W2l = (const float*)d_in[5];
  const float* b2 = (const float*)d_in[6];
  const float* W2r = (const float*)d_in[7];
  const int n = NN;
  const int ne = in_sizes[1] / 2;
  const int nb = NBKT;

  char* base = (char*)d_ws;
  size_t off = 0;
  auto alloc = [&](size_t bytes) -> void* {
    void* r = base + off;
    off = (off + bytes + 255) & ~(size_t)255;
    return r;
  };
  int* flag = (int*)alloc(4);
  int* bcnt = (int*)alloc(512 * 4);
  int* bbase = (int*)alloc(512 * 4);
  int* gcur = (int*)alloc(512 * 4);
  unsigned* binbuf = (unsigned*)alloc((size_t)ne * 4);
  int* rowptr = (int*)alloc((size_t)(n + 1) * 4);
  int* eidx = (int*)alloc((size_t)ne * 4);
  unsigned short* Wc1 = (unsigned short*)alloc(128 * 128 * 2);
  unsigned short* Wc2 = (unsigned short*)alloc(64 * 64 * 2);
  unsigned short* Y1l = (unsigned short*)alloc((size_t)n * 64 * 2);  // bf16 gather table
  float* Y1r = (float*)alloc((size_t)n * 64 * 4);
  unsigned* h = (unsigned*)alloc((size_t)n * 64 * 2);
  unsigned short* Y2l = (unsigned short*)alloc((size_t)n * 32 * 2);
  float* Y2r = (float*)alloc((size_t)n * 32 * 4);
  if (off > ws_size) return;

  k_prep<<<64, 256, 0, stream>>>(W1l, W1r, W2l, W2r, Wc1, Wc2,
                                 (const unsigned*)ei, flag, bcnt);
  k_bhist<<<512, 256, 0, stream>>>(ei, flag, bcnt, ne, nb);
  k_bscan<<<1, 512, 0, stream>>>(bcnt, bbase, gcur, nb, ne);
  k_bin<<<(ne + BIN_CHUNK - 1) / BIN_CHUNK, 256, 0, stream>>>(ei, flag, gcur, binbuf,
                                                              ne, nb);
  k_build<<<nb, 256, 0, stream>>>(binbuf, bbase, rowptr, eidx, n, nb, ne);
  k_gemm<128, 128, false><<<(n + 127) / 128, 256, 0, stream>>>(x, Wc1, Y1l, Y1r, n);
  k_agg1<<<(n + 3) / 4, 256, 0, stream>>>((const unsigned*)Y1l, Y1r, rowptr, eidx, b1, h, n);
  k_gemm<64, 64, true><<<(n + 127) / 128, 256, 0, stream>>>(h, Wc2, Y2l, Y2r, n);
  k_agg2<<<(n + 3) / 4, 256, 0, stream>>>((const unsigned*)Y2l, Y2r, rowptr, eidx, b2,
                                          (float*)d_out, n);
}